// Round 1
// 84.856 us; speedup vs baseline: 1.0461x; 1.0461x over previous
//
#include <hip/hip_runtime.h>
#include <cstdint>

typedef unsigned long long u64;
typedef uint32_t u32;

#define NB 2048
#define EDGE_CAP 16384
#define CLIST_CAP 2048

// ---------------------------------------------------------------------------
// Workspace layout:
//   counters : base +      0 .. 256      (zeroed by hipMemsetAsync)
//   edges    : base + 102400 .. 167936
// Everything else that previously lived in the workspace (rank-permuted
// arrays, pxyr, sidx, sscp) is gone: edges are emitted in ORIGINAL index
// space with score-comparison orientation, so no rank sort is needed.
// ---------------------------------------------------------------------------

// Single fused kernel, 512 blocks x 256 threads (4 i-rows per block):
//   phase 0: block-wide exact max reduction -> offset_scale (bit-identical
//            to the old build_kernel: fmax is order-exact, sqrtf identical)
//   phase 1: register-resident circle sweep over original indices
//   phase 2: heavy rotated-IoU per candidate, geometry recomputed from raw
//            boxes/labels (cosf/sinf identical per element); edges oriented
//            by (s_i > s_j) || (s_i == s_j && i < j)
//   phase 3: last-block election (release/acquire fences) -> greedy
//            fixpoint on the original-index bitmask -> direct output write
__global__ __launch_bounds__(256) void nms_fused_kernel(
    const float* __restrict__ boxes, const float* __restrict__ scores,
    const int* __restrict__ labels, const float* __restrict__ thrp,
    u32* __restrict__ edges, u32* __restrict__ counters,
    float* __restrict__ out) {
#pragma clang fp contract(off)
  __shared__ float sc[NB];
  __shared__ float smc[4], smr[4];
  __shared__ u32 clist[CLIST_CAP];
  __shared__ float dxL[256 * 25];
  __shared__ float dyL[256 * 25];
  __shared__ u32 ccnt;
  __shared__ int is_last;
  __shared__ u64 keepw[32];
  __shared__ u32 Sw32[64];
  __shared__ int changed;
  int t = threadIdx.x;
  if (t == 0) ccnt = 0;
  // ---- phase 0: offset_scale reduction (exact: max order-independent) ----
  float mc = -1e30f, mr = -1e30f;
  for (int k = t; k < NB; k += 256) {
    float cx = boxes[k * 5 + 0];
    float cy = boxes[k * 5 + 1];
    float w = boxes[k * 5 + 2];
    float h = boxes[k * 5 + 3];
    mc = fmaxf(mc, fmaxf(cx, cy));
    float ww = w * w;
    float hh = h * h;
    mr = fmaxf(mr, sqrtf(ww + hh));
    sc[k] = scores[k];
  }
  for (int off = 32; off > 0; off >>= 1) {
    mc = fmaxf(mc, __shfl_down(mc, off));
    mr = fmaxf(mr, __shfl_down(mr, off));
  }
  if ((t & 63) == 0) { smc[t >> 6] = mc; smr[t >> 6] = mr; }
  __syncthreads();   // smc/smr + sc[] + ccnt ready
  mc = fmaxf(fmaxf(smc[0], smc[1]), fmaxf(smc[2], smc[3]));
  mr = fmaxf(fmaxf(smr[0], smr[1]), fmaxf(smr[2], smr[3]));
  float osc = (mc + mr * 0.5f) * 2.0f + 1.0f;

  // ---- register-resident j columns: j = c*256 + t (original indices) ----
  float jx[8], jy[8], jr[8];
#pragma unroll
  for (int c = 0; c < 8; ++c) {
    int j = c * 256 + t;
    float off = (float)labels[j] * osc;
    float w = boxes[j * 5 + 2];
    float h = boxes[j * 5 + 3];
    float ww = w * w;
    float hh = h * h;
    jx[c] = boxes[j * 5 + 0] + off;
    jy[c] = boxes[j * 5 + 1] + off;
    jr[c] = 0.5f * sqrtf(ww + hh);
  }
  // ---- phase 1: circle sweep (broadcast i-loads, coalesced j-regs) ----
  int i0 = blockIdx.x * 4;
#pragma unroll
  for (int di = 0; di < 4; ++di) {
    int i = i0 + di;
    float offi = (float)labels[i] * osc;
    float wI = boxes[i * 5 + 2];
    float hI = boxes[i * 5 + 3];
    float wwI = wI * wI;
    float hhI = hI * hI;
    float ax = boxes[i * 5 + 0] + offi;
    float ay = boxes[i * 5 + 1] + offi;
    float ar = 0.5f * sqrtf(wwI + hhI);
#pragma unroll
    for (int c = 0; c < 8; ++c) {
      int j = c * 256 + t;
      if (j > i) {
        float dx = jx[c] - ax, dy = jy[c] - ay;
        float rr = ar + jr[c] + 1.0f;   // conservative circle pre-test
        if (dx * dx + dy * dy <= rr * rr) {
          u32 s = atomicAdd(&ccnt, 1u);
          if (s < CLIST_CAP) clist[s] = ((u32)i << 16) | (u32)j;
        }
      }
    }
  }
  __syncthreads();
  // ---- phase 2: heavy rotated IoU per candidate ----
  u32 cnt = ccnt < CLIST_CAP ? ccnt : CLIST_CAP;
  float thr = *thrp;
  float* myDx = &dxL[t * 25];
  float* myDy = &dyL[t * 25];
  for (u32 idx = t; idx < cnt; idx += 256) {
    u32 pk = clist[idx];
    int bi = (int)(pk >> 16);
    int bj = (int)(pk & 0xFFFFu);
    float offa = (float)labels[bi] * osc;
    float acx = boxes[bi * 5 + 0] + offa;
    float acy = boxes[bi * 5 + 1] + offa;
    float aw = boxes[bi * 5 + 2];
    float ah = boxes[bi * 5 + 3];
    float aang = boxes[bi * 5 + 4];
    float ac = cosf(aang);
    float as_ = sinf(aang);
    float offb = (float)labels[bj] * osc;
    float bcx = boxes[bj * 5 + 0] + offb;
    float bcy = boxes[bj * 5 + 1] + offb;
    float bw = boxes[bj * 5 + 2];
    float bh = boxes[bj * 5 + 3];
    float bang = boxes[bj * 5 + 4];
    float bc = cosf(bang);
    float bs_ = sinf(bang);
    const float SX[4] = {-1.f, 1.f, 1.f, -1.f};
    const float SY[4] = {-1.f, -1.f, 1.f, 1.f};
    float axx[4], ayy[4], bxx[4], byy[4];
    float ahw = aw * 0.5f, ahh = ah * 0.5f;
    float bhw = bw * 0.5f, bhh = bh * 0.5f;
#pragma unroll
    for (int q = 0; q < 4; ++q) {
      float dx = SX[q] * ahw, dy = SY[q] * ahh;
      axx[q] = acx + ac * dx - as_ * dy;
      ayy[q] = acy + as_ * dx + ac * dy;
      float ex = SX[q] * bhw, ey = SY[q] * bhh;
      bxx[q] = bcx + bc * ex - bs_ * ey;
      byy[q] = bcy + bs_ * ex + bc * ey;
    }
    float px_[24], py_[24];
    bool mk[24];
#pragma unroll
    for (int q = 0; q < 4; ++q) {
      {
        float axp = axx[q] - bcx, ayp = ayy[q] - bcy;
        float lxx = bc * axp + bs_ * ayp;
        float lyy = bc * ayp - bs_ * axp;
        mk[q] = (fabsf(lxx) <= bhw + 1e-5f) && (fabsf(lyy) <= bhh + 1e-5f);
        px_[q] = axx[q]; py_[q] = ayy[q];
      }
      {
        float axp = bxx[q] - acx, ayp = byy[q] - acy;
        float lxx = ac * axp + as_ * ayp;
        float lyy = ac * ayp - as_ * axp;
        mk[4 + q] = (fabsf(lxx) <= ahw + 1e-5f) && (fabsf(lyy) <= ahh + 1e-5f);
        px_[4 + q] = bxx[q]; py_[4 + q] = byy[q];
      }
    }
#pragma unroll
    for (int e = 0; e < 4; ++e) {
      float rx = axx[(e + 1) & 3] - axx[e];
      float ry = ayy[(e + 1) & 3] - ayy[e];
#pragma unroll
      for (int f = 0; f < 4; ++f) {
        float sx = bxx[(f + 1) & 3] - bxx[f];
        float sy = byy[(f + 1) & 3] - byy[f];
        float denom = rx * sy - ry * sx;
        float qpx = bxx[f] - axx[e];
        float qpy = byy[f] - ayy[e];
        bool dn = fabsf(denom) > 1e-9f;
        float safe = dn ? denom : 1.0f;
        float tt = (qpx * sy - qpy * sx) / safe;
        float uu = (qpx * ry - qpy * rx) / safe;
        bool valid = dn && (tt >= 0.0f) && (tt <= 1.0f) && (uu >= 0.0f) && (uu <= 1.0f);
        int id = 8 + e * 4 + f;
        px_[id] = axx[e] + tt * rx;
        py_[id] = ayy[e] + tt * ry;
        mk[id] = valid;
      }
    }
    int k = 0;
    float sx0 = 0.0f, sy0 = 0.0f;
#pragma unroll
    for (int q = 0; q < 24; ++q) {
      if (mk[q]) { k++; sx0 += px_[q]; sy0 += py_[q]; }
    }
    float kkf = (float)(k > 0 ? k : 1);
    float cxm = sx0 / kkf, cym = sy0 / kkf;
    u64 key[32];
#pragma unroll
    for (int q = 0; q < 24; ++q) {
      float dx = px_[q] - cxm, dy = py_[q] - cym;
      myDx[q] = dx; myDy[q] = dy;
      float sm = fabsf(dx) + fabsf(dy);
      float r = (sm > 0.0f) ? dy / sm : 0.0f;
      float pa;
      if (dx >= 0.0f) pa = r;
      else pa = (__float_as_uint(dy) >> 31) ? (-2.0f - r) : (2.0f - r);
      float ang = mk[q] ? pa : 1e9f;
      u32 ub = __float_as_uint(ang);
      u32 v = (ub & 0x80000000u) ? ~ub : (ub | 0x80000000u);
      key[q] = (((u64)v) << 5) | (u64)q;
    }
#pragma unroll
    for (int q = 24; q < 32; ++q) key[q] = ~0ull;
#pragma unroll
    for (int kk2 = 2; kk2 <= 32; kk2 <<= 1) {
#pragma unroll
      for (int jj = kk2 >> 1; jj > 0; jj >>= 1) {
#pragma unroll
        for (int ii = 0; ii < 32; ++ii) {
          int ll = ii ^ jj;
          if (ll > ii) {
            bool up = ((ii & kk2) == 0);
            u64 ka = key[ii], kb = key[ll];
            bool sw = up ? (ka > kb) : (ka < kb);
            key[ii] = sw ? kb : ka;
            key[ll] = sw ? ka : kb;
          }
        }
      }
    }
    float acc = 0.0f;
    int id0 = (int)(key[0] & 31ull);
    float fx = myDx[id0], fy = myDy[id0];
    float curx = fx, cury = fy;
#pragma unroll
    for (int q = 0; q < 24; ++q) {
      if (q < k - 1) {
        int idn = (int)(key[q + 1] & 31ull);
        float nx = myDx[idn], ny = myDy[idn];
        acc += curx * ny - cury * nx;
        curx = nx; cury = ny;
      } else if (q == k - 1) {
        acc += curx * fy - cury * fx;
      }
    }
    float area = 0.5f * fabsf(acc);
    float inter = (k >= 3) ? area : 0.0f;
    float areaA = aw * ah;
    float areaB = bw * bh;
    float iou = inter / (areaA + areaB - inter + 1e-9f);
    if (iou > thr) {
      // orient edge by score rank (stable argsort(-scores) tie-break)
      float si = sc[bi], sj2 = sc[bj];
      bool isup = (si > sj2) || (si == sj2 && bi < bj);
      u32 sup = isup ? (u32)bi : (u32)bj;
      u32 sub = isup ? (u32)bj : (u32)bi;
      u32 e = atomicAdd(&counters[1], 1u);
      if (e < EDGE_CAP) edges[e] = (sup << 16) | sub;
    }
  }
  // ---- publish this block's edges; elect the last-finishing block ----
  __syncthreads();
  if (t == 0) {
    __threadfence();             // release: edges visible device-wide
    u32 old = atomicAdd(&counters[2], 1u);
    is_last = (old == (u32)(gridDim.x - 1)) ? 1 : 0;
  }
  __syncthreads();
  if (!is_last) return;
  __threadfence();               // acquire
  __syncthreads();
  // ---- greedy fixpoint (antitone F => exact sequential-greedy fixpoint) ----
  u32 ecnt = counters[1];
  if (ecnt > EDGE_CAP) ecnt = EDGE_CAP;
  u32 nl = ecnt < CLIST_CAP ? ecnt : CLIST_CAP;
  for (u32 k = t; k < nl; k += 256) clist[k] = edges[k];  // reuse dead clist
  if (t < 32) keepw[t] = ~0ull;
  __syncthreads();
  for (int iter = 0; iter < 2060; ++iter) {
    if (t < 64) Sw32[t] = 0u;
    if (t == 0) changed = 0;
    __syncthreads();
    for (u32 k = t; k < ecnt; k += 256) {
      u32 pk = (k < CLIST_CAP) ? clist[k] : edges[k];
      int i = (int)(pk >> 16);
      int j = (int)(pk & 0xFFFFu);
      if ((keepw[i >> 6] >> (i & 63)) & 1ull)
        atomicOr(&Sw32[j >> 5], 1u << (j & 31));
    }
    __syncthreads();
    if (t < 32) {
      u64 S = ((u64)Sw32[2 * t]) | (((u64)Sw32[2 * t + 1]) << 32);
      u64 nk = ~S;
      if (nk != keepw[t]) { keepw[t] = nk; changed = 1; }
    }
    __syncthreads();
    int ch = changed;
    __syncthreads();
    if (!ch) break;
  }
  // ---- output: direct original-index scatter ----
  for (int p = t; p < NB; p += 256) {
    int bit = (int)((keepw[p >> 6] >> (p & 63)) & 1ull);
    out[p] = bit ? sc[p] : 0.0f;
  }
}

extern "C" void kernel_launch(void* const* d_in, const int* in_sizes, int n_in,
                              void* d_out, int out_size, void* d_ws, size_t ws_size,
                              hipStream_t stream) {
  const float* boxes = (const float*)d_in[0];
  const float* scores = (const float*)d_in[1];
  const int* labels = (const int*)d_in[2];
  const float* thr = (const float*)d_in[3];
  float* out = (float*)d_out;

  char* base = (char*)d_ws;
  u32* counters = (u32*)base;                       // base+0     .. 256
  u32* edges = (u32*)(base + 102400);               // base+102400.. 167936

  hipMemsetAsync(base, 0, 256, stream);             // zero counters (graph-safe memset node)
  nms_fused_kernel<<<512, 256, 0, stream>>>(boxes, scores, labels, thr,
                                            edges, counters, out);
}

// Round 2
// 79.932 us; speedup vs baseline: 1.1106x; 1.0616x over previous
//
#include <hip/hip_runtime.h>
#include <cstdint>

typedef unsigned long long u64;
typedef uint32_t u32;

#define NB 2048
#define NBLK 256
#define SLICE 512            // per-block edge slice capacity
#define CLIST_CAP 2048
#define GCOMP_CAP 131072
#define MAGIC 0x9E3779B1u

// ---------------------------------------------------------------------------
// Workspace layout (no zero-init required anywhere -- memset dispatch gone):
//   edge slices : base +       0 .. 524288   (NBLK * SLICE * 4B)
//   cntA        : base +  524288 .. 525312   (NBLK u32, atomicExch-published)
//   tagA        : base +  525312 .. 526336   (NBLK u32, = cnt ^ MAGIC)
//   gcomp       : base + 1048576 .. 1572864  (compacted-edge overflow >2048)
// Publication is self-validating: poisoned slots fail (cnt^tag)==MAGIC for
// any byte-repeat poison (P^P=0); every partial-staleness coincidence case
// still yields the correct cnt, and tag is only written after the release
// fence, so passing the check implies the edge slice is visible.
// ---------------------------------------------------------------------------

// Single kernel, 256 blocks x 256 threads (8 i-rows per block):
//   phase 0: exact max reduction -> offset_scale (order-exact fmax/sqrtf)
//   phase 1: register-resident circle sweep over original indices
//   phase 2: heavy rotated-IoU per candidate; score-oriented edges into the
//            block's private global slice
//   phase 3: publish (fence + atomicExch cnt/tag); block 0 spins on all 256
//            publications (coherence-point atomic reads), acquire-fences,
//            prefix-sums + compacts edges, runs the greedy fixpoint, writes
//            the output directly in original index space.
__global__ __launch_bounds__(256) void nms_fused_kernel(
    const float* __restrict__ boxes, const float* __restrict__ scores,
    const int* __restrict__ labels, const float* __restrict__ thrp,
    u32* __restrict__ edges, u32* __restrict__ cntA, u32* __restrict__ tagA,
    u32* __restrict__ gcomp, float* __restrict__ out) {
#pragma clang fp contract(off)
  __shared__ float sc[NB];
  __shared__ float smc[4], smr[4];
  __shared__ u32 clist[CLIST_CAP];
  __shared__ float dxL[256 * 25];
  __shared__ float dyL[256 * 25];
  __shared__ u32 ccnt;      // candidate count (LDS)
  __shared__ u32 ecntL;     // edge count for this block (LDS)
  __shared__ u32 cntL[NBLK];
  __shared__ u32 sA[NBLK];
  __shared__ u64 keepw[32];
  __shared__ u32 Sw32[64];
  __shared__ int changed;
  int t = threadIdx.x;
  int b = blockIdx.x;
  if (t == 0) { ccnt = 0; ecntL = 0; }
  // ---- phase 0: offset_scale reduction (exact: max order-independent) ----
  float mc = -1e30f, mr = -1e30f;
  for (int k = t; k < NB; k += 256) {
    float cx = boxes[k * 5 + 0];
    float cy = boxes[k * 5 + 1];
    float w = boxes[k * 5 + 2];
    float h = boxes[k * 5 + 3];
    mc = fmaxf(mc, fmaxf(cx, cy));
    float ww = w * w;
    float hh = h * h;
    mr = fmaxf(mr, sqrtf(ww + hh));
    sc[k] = scores[k];
  }
  for (int off = 32; off > 0; off >>= 1) {
    mc = fmaxf(mc, __shfl_down(mc, off));
    mr = fmaxf(mr, __shfl_down(mr, off));
  }
  if ((t & 63) == 0) { smc[t >> 6] = mc; smr[t >> 6] = mr; }
  __syncthreads();   // smc/smr + sc[] + ccnt/ecntL ready
  mc = fmaxf(fmaxf(smc[0], smc[1]), fmaxf(smc[2], smc[3]));
  mr = fmaxf(fmaxf(smr[0], smr[1]), fmaxf(smr[2], smr[3]));
  float osc = (mc + mr * 0.5f) * 2.0f + 1.0f;

  // ---- register-resident j columns: j = c*256 + t (original indices) ----
  float jx[8], jy[8], jr[8];
#pragma unroll
  for (int c = 0; c < 8; ++c) {
    int j = c * 256 + t;
    float off = (float)labels[j] * osc;
    float w = boxes[j * 5 + 2];
    float h = boxes[j * 5 + 3];
    float ww = w * w;
    float hh = h * h;
    jx[c] = boxes[j * 5 + 0] + off;
    jy[c] = boxes[j * 5 + 1] + off;
    jr[c] = 0.5f * sqrtf(ww + hh);
  }
  // ---- phase 1: circle sweep (broadcast i-loads, coalesced j-regs) ----
  int i0 = b * 8;
#pragma unroll
  for (int di = 0; di < 8; ++di) {
    int i = i0 + di;
    float offi = (float)labels[i] * osc;
    float wI = boxes[i * 5 + 2];
    float hI = boxes[i * 5 + 3];
    float wwI = wI * wI;
    float hhI = hI * hI;
    float ax = boxes[i * 5 + 0] + offi;
    float ay = boxes[i * 5 + 1] + offi;
    float ar = 0.5f * sqrtf(wwI + hhI);
#pragma unroll
    for (int c = 0; c < 8; ++c) {
      int j = c * 256 + t;
      if (j > i) {
        float dx = jx[c] - ax, dy = jy[c] - ay;
        float rr = ar + jr[c] + 1.0f;   // conservative circle pre-test
        if (dx * dx + dy * dy <= rr * rr) {
          u32 s = atomicAdd(&ccnt, 1u);
          if (s < CLIST_CAP) clist[s] = ((u32)i << 16) | (u32)j;
        }
      }
    }
  }
  __syncthreads();
  // ---- phase 2: heavy rotated IoU per candidate ----
  u32 cnt = ccnt < CLIST_CAP ? ccnt : CLIST_CAP;
  float thr = *thrp;
  u32* myEdges = edges + (u32)b * SLICE;
  float* myDx = &dxL[t * 25];
  float* myDy = &dyL[t * 25];
  for (u32 idx = t; idx < cnt; idx += 256) {
    u32 pk = clist[idx];
    int bi = (int)(pk >> 16);
    int bj = (int)(pk & 0xFFFFu);
    float offa = (float)labels[bi] * osc;
    float acx = boxes[bi * 5 + 0] + offa;
    float acy = boxes[bi * 5 + 1] + offa;
    float aw = boxes[bi * 5 + 2];
    float ah = boxes[bi * 5 + 3];
    float aang = boxes[bi * 5 + 4];
    float ac = cosf(aang);
    float as_ = sinf(aang);
    float offb = (float)labels[bj] * osc;
    float bcx = boxes[bj * 5 + 0] + offb;
    float bcy = boxes[bj * 5 + 1] + offb;
    float bw = boxes[bj * 5 + 2];
    float bh = boxes[bj * 5 + 3];
    float bang = boxes[bj * 5 + 4];
    float bc = cosf(bang);
    float bs_ = sinf(bang);
    const float SX[4] = {-1.f, 1.f, 1.f, -1.f};
    const float SY[4] = {-1.f, -1.f, 1.f, 1.f};
    float axx[4], ayy[4], bxx[4], byy[4];
    float ahw = aw * 0.5f, ahh = ah * 0.5f;
    float bhw = bw * 0.5f, bhh = bh * 0.5f;
#pragma unroll
    for (int q = 0; q < 4; ++q) {
      float dx = SX[q] * ahw, dy = SY[q] * ahh;
      axx[q] = acx + ac * dx - as_ * dy;
      ayy[q] = acy + as_ * dx + ac * dy;
      float ex = SX[q] * bhw, ey = SY[q] * bhh;
      bxx[q] = bcx + bc * ex - bs_ * ey;
      byy[q] = bcy + bs_ * ex + bc * ey;
    }
    float px_[24], py_[24];
    bool mk[24];
#pragma unroll
    for (int q = 0; q < 4; ++q) {
      {
        float axp = axx[q] - bcx, ayp = ayy[q] - bcy;
        float lxx = bc * axp + bs_ * ayp;
        float lyy = bc * ayp - bs_ * axp;
        mk[q] = (fabsf(lxx) <= bhw + 1e-5f) && (fabsf(lyy) <= bhh + 1e-5f);
        px_[q] = axx[q]; py_[q] = ayy[q];
      }
      {
        float axp = bxx[q] - acx, ayp = byy[q] - acy;
        float lxx = ac * axp + as_ * ayp;
        float lyy = ac * ayp - as_ * axp;
        mk[4 + q] = (fabsf(lxx) <= ahw + 1e-5f) && (fabsf(lyy) <= ahh + 1e-5f);
        px_[4 + q] = bxx[q]; py_[4 + q] = byy[q];
      }
    }
#pragma unroll
    for (int e = 0; e < 4; ++e) {
      float rx = axx[(e + 1) & 3] - axx[e];
      float ry = ayy[(e + 1) & 3] - ayy[e];
#pragma unroll
      for (int f = 0; f < 4; ++f) {
        float sx = bxx[(f + 1) & 3] - bxx[f];
        float sy = byy[(f + 1) & 3] - byy[f];
        float denom = rx * sy - ry * sx;
        float qpx = bxx[f] - axx[e];
        float qpy = byy[f] - ayy[e];
        bool dn = fabsf(denom) > 1e-9f;
        float safe = dn ? denom : 1.0f;
        float tt = (qpx * sy - qpy * sx) / safe;
        float uu = (qpx * ry - qpy * rx) / safe;
        bool valid = dn && (tt >= 0.0f) && (tt <= 1.0f) && (uu >= 0.0f) && (uu <= 1.0f);
        int id = 8 + e * 4 + f;
        px_[id] = axx[e] + tt * rx;
        py_[id] = ayy[e] + tt * ry;
        mk[id] = valid;
      }
    }
    int k = 0;
    float sx0 = 0.0f, sy0 = 0.0f;
#pragma unroll
    for (int q = 0; q < 24; ++q) {
      if (mk[q]) { k++; sx0 += px_[q]; sy0 += py_[q]; }
    }
    float kkf = (float)(k > 0 ? k : 1);
    float cxm = sx0 / kkf, cym = sy0 / kkf;
    u64 key[32];
#pragma unroll
    for (int q = 0; q < 24; ++q) {
      float dx = px_[q] - cxm, dy = py_[q] - cym;
      myDx[q] = dx; myDy[q] = dy;
      float sm = fabsf(dx) + fabsf(dy);
      float r = (sm > 0.0f) ? dy / sm : 0.0f;
      float pa;
      if (dx >= 0.0f) pa = r;
      else pa = (__float_as_uint(dy) >> 31) ? (-2.0f - r) : (2.0f - r);
      float ang = mk[q] ? pa : 1e9f;
      u32 ub = __float_as_uint(ang);
      u32 v = (ub & 0x80000000u) ? ~ub : (ub | 0x80000000u);
      key[q] = (((u64)v) << 5) | (u64)q;
    }
#pragma unroll
    for (int q = 24; q < 32; ++q) key[q] = ~0ull;
#pragma unroll
    for (int kk2 = 2; kk2 <= 32; kk2 <<= 1) {
#pragma unroll
      for (int jj = kk2 >> 1; jj > 0; jj >>= 1) {
#pragma unroll
        for (int ii = 0; ii < 32; ++ii) {
          int ll = ii ^ jj;
          if (ll > ii) {
            bool up = ((ii & kk2) == 0);
            u64 ka = key[ii], kb = key[ll];
            bool sw = up ? (ka > kb) : (ka < kb);
            key[ii] = sw ? kb : ka;
            key[ll] = sw ? ka : kb;
          }
        }
      }
    }
    float acc = 0.0f;
    int id0 = (int)(key[0] & 31ull);
    float fx = myDx[id0], fy = myDy[id0];
    float curx = fx, cury = fy;
#pragma unroll
    for (int q = 0; q < 24; ++q) {
      if (q < k - 1) {
        int idn = (int)(key[q + 1] & 31ull);
        float nx = myDx[idn], ny = myDy[idn];
        acc += curx * ny - cury * nx;
        curx = nx; cury = ny;
      } else if (q == k - 1) {
        acc += curx * fy - cury * fx;
      }
    }
    float area = 0.5f * fabsf(acc);
    float inter = (k >= 3) ? area : 0.0f;
    float areaA = aw * ah;
    float areaB = bw * bh;
    float iou = inter / (areaA + areaB - inter + 1e-9f);
    if (iou > thr) {
      // orient edge by score rank (stable argsort(-scores) tie-break)
      float si = sc[bi], sj2 = sc[bj];
      bool isup = (si > sj2) || (si == sj2 && bi < bj);
      u32 sup = isup ? (u32)bi : (u32)bj;
      u32 sub = isup ? (u32)bj : (u32)bi;
      u32 e = atomicAdd(&ecntL, 1u);
      if (e < SLICE) myEdges[e] = (sup << 16) | sub;
    }
  }
  // ---- phase 3a: publish this block's slice (release + coherent publish) ----
  __syncthreads();
  if (t == 0) {
    u32 myc = ecntL < SLICE ? ecntL : SLICE;
    __threadfence();                 // release: edge slice visible device-wide
    atomicExch(&cntA[b], myc);       // coherence-point publish
    atomicExch(&tagA[b], myc ^ MAGIC);
  }
  if (b != 0) return;
  // ---- phase 3b (block 0 only): spin for all publications ----
  {
    u32 c;
    for (;;) {
      c = atomicOr(&cntA[t], 0u);    // coherence-point read, L1/L2-safe
      u32 g = atomicOr(&tagA[t], 0u);
      if ((c ^ g) == MAGIC) break;
    }
    cntL[t] = c;
  }
  __syncthreads();
  __threadfence();                   // acquire: edge slices now readable
  // ---- inclusive scan of cntL (Hillis-Steele, 8 steps) ----
  sA[t] = cntL[t];
  __syncthreads();
#pragma unroll
  for (int d = 1; d < NBLK; d <<= 1) {
    u32 u = (t >= d) ? sA[t - d] : 0u;
    __syncthreads();
    sA[t] += u;
    __syncthreads();
  }
  u32 total = sA[NBLK - 1];
  if (total > GCOMP_CAP) total = GCOMP_CAP;
  // ---- compaction: thread t copies slice t into clist/gcomp ----
  {
    u32 cb = cntL[t];
    u32 off = sA[t] - cb;
    const u32* slice = edges + (u32)t * SLICE;
    for (u32 k2 = 0; k2 < cb; ++k2) {
      u32 pos = off + k2;
      u32 val = slice[k2];
      if (pos < CLIST_CAP) clist[pos] = val;
      else if (pos < GCOMP_CAP) gcomp[pos] = val;
    }
  }
  if (t < 32) keepw[t] = ~0ull;
  __syncthreads();
  // ---- greedy fixpoint (antitone F => exact sequential-greedy fixpoint) ----
  for (int iter = 0; iter < 2060; ++iter) {
    if (t < 64) Sw32[t] = 0u;
    if (t == 0) changed = 0;
    __syncthreads();
    for (u32 k = t; k < total; k += 256) {
      u32 pk = (k < CLIST_CAP) ? clist[k] : gcomp[k];
      int i = (int)(pk >> 16);
      int j = (int)(pk & 0xFFFFu);
      if ((keepw[i >> 6] >> (i & 63)) & 1ull)
        atomicOr(&Sw32[j >> 5], 1u << (j & 31));
    }
    __syncthreads();
    if (t < 32) {
      u64 S = ((u64)Sw32[2 * t]) | (((u64)Sw32[2 * t + 1]) << 32);
      u64 nk = ~S;
      if (nk != keepw[t]) { keepw[t] = nk; changed = 1; }
    }
    __syncthreads();
    int ch = changed;
    __syncthreads();
    if (!ch) break;
  }
  // ---- output: direct original-index write ----
  for (int p = t; p < NB; p += 256) {
    int bit = (int)((keepw[p >> 6] >> (p & 63)) & 1ull);
    out[p] = bit ? sc[p] : 0.0f;
  }
}

extern "C" void kernel_launch(void* const* d_in, const int* in_sizes, int n_in,
                              void* d_out, int out_size, void* d_ws, size_t ws_size,
                              hipStream_t stream) {
  const float* boxes = (const float*)d_in[0];
  const float* scores = (const float*)d_in[1];
  const int* labels = (const int*)d_in[2];
  const float* thr = (const float*)d_in[3];
  float* out = (float*)d_out;

  char* base = (char*)d_ws;
  u32* edges = (u32*)base;                          // base+0       .. 524288
  u32* cntA = (u32*)(base + 524288);                // base+524288  .. 525312
  u32* tagA = (u32*)(base + 525312);                // base+525312  .. 526336
  u32* gcomp = (u32*)(base + 1048576);              // base+1048576 .. 1572864

  nms_fused_kernel<<<NBLK, 256, 0, stream>>>(boxes, scores, labels, thr,
                                             edges, cntA, tagA, gcomp, out);
}